// Round 12
// baseline (290.442 us; speedup 1.0000x reference)
//
#include <hip/hip_runtime.h>
#include <hip/hip_bf16.h>
#include <math.h>

namespace {
constexpr int kD = 256;      // embed dim
constexpr int kDOUT = 256;   // out dim
constexpr int kNQ = 65536;   // num query nodes
constexpr int kE = 262144;   // edges
constexpr float kAlpha = 0.2f;
constexpr float kEps = 1e-12f;
constexpr int kCap = 16;     // slots per query (P(deg>16) ~ 1e-6 per query)
constexpr int kOvfMax = 4096;
}

typedef short bf16x8 __attribute__((ext_vector_type(8)));
typedef float f32x4 __attribute__((ext_vector_type(4)));
typedef unsigned short u16x8 __attribute__((ext_vector_type(8)));

static __device__ __forceinline__ float bf2f(unsigned short u) {
  union { unsigned int i; float f; } v;
  v.i = ((unsigned int)u) << 16;
  return v.f;
}

// c[j] = sum_k a[k][j] * a2[k]   (a is (DOUT, 2D) row-major; j in [0, 512))
__global__ void compute_c_kernel(const float* __restrict__ a,
                                 const float* __restrict__ a2,
                                 float* __restrict__ c) {
  const int j = blockIdx.x * blockDim.x + threadIdx.x;  // 0..511
  float s = 0.f;
#pragma unroll 8
  for (int k = 0; k < kDOUT; ++k) s = fmaf(a[k * (2 * kD) + j], a2[k], s);
  c[j] = s;
}

// zero count[NQ] (ints) + rowsum[NQ] (floats) + ovf_n
__global__ void zero_kernel(int4* __restrict__ p, int* __restrict__ ovf_n) {
  p[blockIdx.x * 256 + threadIdx.x] = int4{0, 0, 0, 0};
  if (blockIdx.x == 0 && threadIdx.x == 0) *ovf_n = 0;
}

// trans (256x256 f32) -> bf16
__global__ void cvt_trans_kernel(const float* __restrict__ t, ushort* __restrict__ tb) {
  const int i = blockIdx.x * 256 + threadIdx.x;  // 4 elems each
  const float4 v = reinterpret_cast<const float4*>(t)[i];
  union { ushort4 u; __hip_bfloat16 h[4]; } p;
  p.h[0] = __float2bfloat16(v.x);
  p.h[1] = __float2bfloat16(v.y);
  p.h[2] = __float2bfloat16(v.z);
  p.h[3] = __float2bfloat16(v.w);
  reinterpret_cast<ushort4*>(tb)[i] = p.u;
}

// Sweep: each wave processes 4 edges per iteration, 8 iterations.
// Latency-batched: (1) 4 slot atomics issued first (lanes 0-3),
// (2) all 8 row loads (8KB/wave) issued, (3) four dot/reduce/exp chains,
// (4) rowsum atomics 4-wide, (5) four 512B capacity-bin stores.
__global__ __launch_bounds__(256) void sweep_kernel(
    const float* __restrict__ key_embed,
    const float* __restrict__ query_embed,
    const int* __restrict__ qlist,
    const float* __restrict__ c,
    int* __restrict__ count,
    float* __restrict__ rowsum,
    int* __restrict__ ovf_n,
    int* __restrict__ ovf_q,
    ushort* __restrict__ wovf,
    ushort* __restrict__ wkey) {
  const int wid = threadIdx.x >> 6;
  const int lane = threadIdx.x & 63;
  const int ebase = blockIdx.x * 128 + wid * 32;   // wave: 32 edges, 8 iters of 4

  const float4 ck = reinterpret_cast<const float4*>(c)[lane];
  const float4 cq = reinterpret_cast<const float4*>(c)[64 + lane];
  const float4* kp = reinterpret_cast<const float4*>(key_embed);
  const float4* qp = reinterpret_cast<const float4*>(query_embed);

  for (int it = 0; it < 8; ++it) {
    const int e0 = ebase + it * 4;

    // (1) slot atomics first — 4 independent, on lanes 0-3
    int q_l = 0, slot_l = 0;
    if (lane < 4) {
      q_l = qlist[e0 + lane];
      slot_l = atomicAdd(&count[q_l], 1);
    }

    // (2) all 8 independent row loads
    float4 k4[4], q4[4];
#pragma unroll
    for (int t = 0; t < 4; ++t) k4[t] = kp[(size_t)(e0 + t) * 64 + lane];
#pragma unroll
    for (int t = 0; t < 4; ++t) q4[t] = qp[(size_t)(e0 + t) * 64 + lane];

    // (3) four dot -> reduce -> exp chains
    float ev[4];
#pragma unroll
    for (int t = 0; t < 4; ++t) {
      float s = k4[t].x * ck.x + k4[t].y * ck.y + k4[t].z * ck.z + k4[t].w * ck.w
              + q4[t].x * cq.x + q4[t].y * cq.y + q4[t].z * cq.z + q4[t].w * cq.w;
#pragma unroll
      for (int off = 1; off < 64; off <<= 1) s += __shfl_xor(s, off, 64);
      const float p = (s > 0.f) ? s : kAlpha * s;   // leaky_relu
      ev[t] = __expf(-p);
    }

    // (4) rowsum atomics, 4-wide on lanes 0-3 (static select, no dyn index)
    const float evs = (lane == 0) ? ev[0] : (lane == 1) ? ev[1]
                    : (lane == 2) ? ev[2] : ev[3];
    if (lane < 4) unsafeAtomicAdd(&rowsum[q_l], evs);

    // (5) four 512B stores to capacity bins
#pragma unroll
    for (int t = 0; t < 4; ++t) {
      const int qt = __shfl(q_l, t, 64);
      const int st = __shfl(slot_l, t, 64);
      union { ushort4 u; __hip_bfloat16 h[4]; } pk;
      pk.h[0] = __float2bfloat16(ev[t] * k4[t].x);
      pk.h[1] = __float2bfloat16(ev[t] * k4[t].y);
      pk.h[2] = __float2bfloat16(ev[t] * k4[t].z);
      pk.h[3] = __float2bfloat16(ev[t] * k4[t].w);
      if (st < kCap) {
        *reinterpret_cast<ushort4*>(wkey + ((size_t)qt * kCap + st) * kD + lane * 4) = pk.u;
      } else {                       // rare overflow (uniform branch)
        int o = 0;
        if (lane == 0) {
          o = atomicAdd(ovf_n, 1);
          if (o < kOvfMax) ovf_q[o] = qt;
        }
        o = __shfl(o, 0, 64);
        if (o < kOvfMax)
          *reinterpret_cast<ushort4*>(wovf + (size_t)o * kD + lane * 4) = pk.u;
      }
    }
  }
}

// Gather: 2 queries per wave (32 lanes each). Reads the query's CONTIGUOUS
// capacity-bin rows (deg x 512B granule), 4 rows unrolled/in-flight;
// adds rare overflow entries; normalizes by rowsum; coalesced bf16 write.
__global__ __launch_bounds__(256) void gather_kernel(
    const ushort* __restrict__ wkey,
    const ushort* __restrict__ wovf,
    const int* __restrict__ ovf_q,
    const int* __restrict__ ovf_n,
    const int* __restrict__ count,
    const float* __restrict__ rowsum,
    ushort* __restrict__ accb) {
  const int wid = threadIdx.x >> 6;
  const int lane = threadIdx.x & 63;
  const int g = lane >> 5;
  const int l5 = lane & 31;
  const int q = blockIdx.x * 8 + wid * 2 + g;

  const int cnt = count[q];
  const int cm = min(cnt, kCap);
  const ushort* base = wkey + (size_t)q * kCap * kD + l5 * 8;

  float acc[8] = {};
  int r = 0;
  for (; r + 4 <= cm; r += 4) {
    const u16x8 u0 = *reinterpret_cast<const u16x8*>(base + (size_t)(r + 0) * kD);
    const u16x8 u1 = *reinterpret_cast<const u16x8*>(base + (size_t)(r + 1) * kD);
    const u16x8 u2 = *reinterpret_cast<const u16x8*>(base + (size_t)(r + 2) * kD);
    const u16x8 u3 = *reinterpret_cast<const u16x8*>(base + (size_t)(r + 3) * kD);
#pragma unroll
    for (int j = 0; j < 8; ++j)
      acc[j] += (bf2f((unsigned short)u0[j]) + bf2f((unsigned short)u1[j])) +
                (bf2f((unsigned short)u2[j]) + bf2f((unsigned short)u3[j]));
  }
  for (; r < cm; ++r) {
    const u16x8 u = *reinterpret_cast<const u16x8*>(base + (size_t)r * kD);
#pragma unroll
    for (int j = 0; j < 8; ++j) acc[j] += bf2f((unsigned short)u[j]);
  }

  if (cnt > kCap) {   // rare: scan the tiny overflow list
    const int n = min(*ovf_n, kOvfMax);
    for (int i = 0; i < n; ++i) {
      if (ovf_q[i] == q) {
        const u16x8 u = *reinterpret_cast<const u16x8*>(wovf + (size_t)i * kD + l5 * 8);
#pragma unroll
        for (int j = 0; j < 8; ++j) acc[j] += bf2f((unsigned short)u[j]);
      }
    }
  }

  const float rs = rowsum[q];
  const float inv = 1.0f / ((rs == 0.f) ? kEps : rs);
  union { u16x8 u; __hip_bfloat16 h[8]; } pk;
#pragma unroll
  for (int j = 0; j < 8; ++j) pk.h[j] = __float2bfloat16(acc[j] * inv);
  *reinterpret_cast<u16x8*>(accb + (size_t)q * kD + l5 * 8) = pk.u;
}

// out = elu(A @ B^T).  A: (NQ,256) bf16 row-major (pre-normalized), B = trans bf16.
// One wave per 16-row strip, full N=256 in registers (16 n-tiles of 16x16x32 MFMA).
__global__ __launch_bounds__(256) void out_gemm_mfma_kernel(
    const ushort* __restrict__ A,
    const ushort* __restrict__ B,
    float* __restrict__ out) {
  const int wid = threadIdx.x >> 6;
  const int lane = threadIdx.x & 63;
  const int row0 = (blockIdx.x * 4 + wid) * 16;
  const int m = lane & 15;
  const int kb = (lane >> 4) * 8;

  f32x4 acc[16] = {};

  for (int kt = 0; kt < kD; kt += 32) {
    const bf16x8 af = *reinterpret_cast<const bf16x8*>(&A[(size_t)(row0 + m) * kD + kt + kb]);
#pragma unroll
    for (int nt = 0; nt < 16; ++nt) {
      const bf16x8 bf = *reinterpret_cast<const bf16x8*>(&B[(size_t)(nt * 16 + m) * kD + kt + kb]);
      acc[nt] = __builtin_amdgcn_mfma_f32_16x16x32_bf16(af, bf, acc[nt], 0, 0, 0);
    }
  }

#pragma unroll
  for (int nt = 0; nt < 16; ++nt) {
#pragma unroll
    for (int r = 0; r < 4; ++r) {
      const int row = row0 + (lane >> 4) * 4 + r;
      const int col = nt * 16 + (lane & 15);
      const float x = acc[nt][r];
      out[(size_t)row * kDOUT + col] = (x > 0.f) ? x : expm1f(x);
    }
  }
}

extern "C" void kernel_launch(void* const* d_in, const int* in_sizes, int n_in,
                              void* d_out, int out_size, void* d_ws, size_t ws_size,
                              hipStream_t stream) {
  // inputs: 0 key_list(int,E) [unused], 1 key_embed(f32,E*256), 2 query_list(int,E),
  //         3 query_embed(f32,E*256), 4 a(f32,256*512), 5 a_2(f32,256), 6 trans(f32,256*256)
  const float* key_embed = (const float*)d_in[1];
  const int* query_list = (const int*)d_in[2];
  const float* query_embed = (const float*)d_in[3];
  const float* a = (const float*)d_in[4];
  const float* a2 = (const float*)d_in[5];
  const float* trans = (const float*)d_in[6];
  float* out = (float*)d_out;

  // workspace layout (ushort units from base; wkey first for alignment):
  // wkey[NQ*16*256 us = 512MB] | accb[NQ*256 us] | transb[256*256 us]
  // | wovf[kOvfMax*256 us] | c[512 f] | count[NQ i] | rowsum[NQ f] | ovf_n[4 i] | ovf_q[kOvfMax i]
  ushort* wkey = (ushort*)d_ws;
  ushort* accb = wkey + (size_t)kNQ * kCap * kD;
  ushort* transb = accb + (size_t)kNQ * kD;
  ushort* wovf = transb + (size_t)kDOUT * kD;
  float* c = (float*)(wovf + (size_t)kOvfMax * kD);
  int* count = (int*)(c + 512);
  float* rowsum = (float*)(count + kNQ);
  int* ovf_n = (int*)(rowsum + kNQ);
  int* ovf_q = ovf_n + 4;

  // zero count + rowsum (contiguous, 2*kNQ ints) + ovf_n
  zero_kernel<<<2 * kNQ / 4 / 256, 256, 0, stream>>>((int4*)count, ovf_n);
  compute_c_kernel<<<2, 256, 0, stream>>>(a, a2, c);
  cvt_trans_kernel<<<kDOUT * kD / 4 / 256, 256, 0, stream>>>(trans, transb);
  sweep_kernel<<<kE / 128, 256, 0, stream>>>(key_embed, query_embed, query_list, c,
                                             count, rowsum, ovf_n, ovf_q, wovf, wkey);
  gather_kernel<<<kNQ / 8, 256, 0, stream>>>(wkey, wovf, ovf_q, ovf_n, count, rowsum, accb);
  out_gemm_mfma_kernel<<<kNQ / 64, 256, 0, stream>>>(accb, transb, out);
}